// Round 1
// baseline (58.817 us; speedup 1.0000x reference)
//
#include <hip/hip_runtime.h>
#include <math.h>

// Problem: B=64, T=512, D=1024.
//   v[b,d]     = sum_e W[d,e] * x[b,T-1,e]
//   scores[b,t]= sum_d x[b,t,d] * v[b,d]          (t in 0..510)
//   alpha      = softmax_t(scores)
//   c[b,d]     = sum_t alpha[b,t] * x[b,t,d]
//   out[b]     = concat(c[b,:], x[b,T-1,:])       (64 x 2048 fp32)

#define BB 64
#define TT 512
#define DD 1024
#define TH 511           // history rows
#define CHUNK 16         // t-rows per block in fused pass
#define NCHUNK 32        // ceil(511/16)

// workspace layout (floats):
//   v      : [BB][DD]              off 0        (65536)
//   partC  : [BB][NCHUNK][DD]      off 65536    (2097152)
//   partML : [BB][NCHUNK][2]       off 2162688  (4096)
// total ~8.7 MB

// ---------------- kernel 1: v = x_last @ W^T -------------------------------
// one wave per d-row; W row stationary in 16 VGPRs; loop batches.
__global__ __launch_bounds__(256) void k_v(const float* __restrict__ x,
                                           const float* __restrict__ W,
                                           float* __restrict__ v) {
    const int wave = threadIdx.x >> 6;
    const int lane = threadIdx.x & 63;
    const int d    = blockIdx.x * 4 + wave;     // 256 blocks * 4 waves = 1024 rows

    float4 w4[4];
#pragma unroll
    for (int j = 0; j < 4; ++j)
        w4[j] = *(const float4*)(W + (size_t)d * DD + j * 256 + lane * 4);

    float res = 0.f;                            // lane l keeps v[b=l][d]
    for (int b = 0; b < BB; ++b) {
        const float* xl = x + ((size_t)b * TT + (TT - 1)) * DD;
        float p = 0.f;
#pragma unroll
        for (int j = 0; j < 4; ++j) {
            float4 xv = *(const float4*)(xl + j * 256 + lane * 4);
            p += w4[j].x * xv.x + w4[j].y * xv.y + w4[j].z * xv.z + w4[j].w * xv.w;
        }
#pragma unroll
        for (int m = 1; m < 64; m <<= 1) p += __shfl_xor(p, m, 64);
        if (lane == b) res = p;                 // butterfly: every lane has sum
    }
    v[(size_t)lane * DD + d] = res;
}

// ---------------- kernel 2: fused scores -> chunk softmax -> partial c -----
// grid = BB * NCHUNK blocks, 256 threads, 64KB LDS (2 blocks/CU).
__global__ __launch_bounds__(256) void k_chunk(const float* __restrict__ x,
                                               const float* __restrict__ v,
                                               float* __restrict__ partC,
                                               float* __restrict__ partML) {
    __shared__ float xs[CHUNK][DD];             // 64 KB
    __shared__ float sloc[CHUNK];
    __shared__ float eloc[CHUNK];

    const int b    = blockIdx.x >> 5;           // / NCHUNK
    const int c    = blockIdx.x & (NCHUNK - 1);
    const int wave = threadIdx.x >> 6;
    const int lane = threadIdx.x & 63;
    const int R    = min(CHUNK, TH - c * CHUNK);   // 16, last chunk 15

    // per-lane fragment of v[b,:]
    float4 v4[4];
#pragma unroll
    for (int j = 0; j < 4; ++j)
        v4[j] = *(const float4*)(v + (size_t)b * DD + j * 256 + lane * 4);

    const float* xb = x + ((size_t)b * TT + (size_t)c * CHUNK) * DD;

    // phase A: stream rows from HBM -> LDS, dot with v, wave-reduce score
#pragma unroll
    for (int k = 0; k < 4; ++k) {
        const int r = wave + 4 * k;
        if (r < R) {
            float p = 0.f;
#pragma unroll
            for (int j = 0; j < 4; ++j) {
                float4 xv = *(const float4*)(xb + (size_t)r * DD + j * 256 + lane * 4);
                *(float4*)(&xs[r][j * 256 + lane * 4]) = xv;
                p += v4[j].x * xv.x + v4[j].y * xv.y + v4[j].z * xv.z + v4[j].w * xv.w;
            }
#pragma unroll
            for (int m = 1; m < 64; m <<= 1) p += __shfl_xor(p, m, 64);
            if (lane == 0) sloc[r] = p;
        }
    }
    __syncthreads();

    // phase B: chunk-local softmax stats (redundant per-thread, LDS broadcast)
    float m = -INFINITY;
    for (int r = 0; r < R; ++r) m = fmaxf(m, sloc[r]);
    if (threadIdx.x < R) eloc[threadIdx.x] = expf(sloc[threadIdx.x] - m);
    __syncthreads();
    float l = 0.f;
    for (int r = 0; r < R; ++r) l += eloc[r];

    // phase C: partial c = sum_r e_r * x_r  (each thread owns 4 d's)
    const int d0 = threadIdx.x * 4;
    float4 acc = {0.f, 0.f, 0.f, 0.f};
    for (int r = 0; r < R; ++r) {
        const float e = eloc[r];
        float4 xv = *(const float4*)(&xs[r][d0]);
        acc.x += e * xv.x; acc.y += e * xv.y; acc.z += e * xv.z; acc.w += e * xv.w;
    }
    *(float4*)(partC + ((size_t)b * NCHUNK + c) * DD + d0) = acc;
    if (threadIdx.x == 0) {
        partML[((size_t)b * NCHUNK + c) * 2 + 0] = m;
        partML[((size_t)b * NCHUNK + c) * 2 + 1] = l;
    }
}

// ---------------- kernel 3: combine partials, divide, append x_last --------
__global__ __launch_bounds__(256) void k_final(const float* __restrict__ x,
                                               const float* __restrict__ partC,
                                               const float* __restrict__ partML,
                                               float* __restrict__ out) {
    const int b = blockIdx.x;
    __shared__ float wgt[NCHUNK];

    float M = -INFINITY;
    for (int c = 0; c < NCHUNK; ++c)
        M = fmaxf(M, partML[((size_t)b * NCHUNK + c) * 2]);
    if (threadIdx.x < NCHUNK)
        wgt[threadIdx.x] = expf(partML[((size_t)b * NCHUNK + threadIdx.x) * 2] - M);
    __syncthreads();
    float L = 0.f;
    for (int c = 0; c < NCHUNK; ++c)
        L += partML[((size_t)b * NCHUNK + c) * 2 + 1] * wgt[c];
    const float invL = 1.f / L;

    const int d0 = threadIdx.x * 4;
    float4 acc = {0.f, 0.f, 0.f, 0.f};
    for (int c = 0; c < NCHUNK; ++c) {
        float4 p = *(const float4*)(partC + ((size_t)b * NCHUNK + c) * DD + d0);
        const float w = wgt[c];
        acc.x += w * p.x; acc.y += w * p.y; acc.z += w * p.z; acc.w += w * p.w;
    }
    float4 o = {acc.x * invL, acc.y * invL, acc.z * invL, acc.w * invL};
    *(float4*)(out + (size_t)b * 2048 + d0) = o;

    float4 xl = *(const float4*)(x + ((size_t)b * TT + (TT - 1)) * DD + d0);
    *(float4*)(out + (size_t)b * 2048 + 1024 + d0) = xl;
}

extern "C" void kernel_launch(void* const* d_in, const int* in_sizes, int n_in,
                              void* d_out, int out_size, void* d_ws, size_t ws_size,
                              hipStream_t stream) {
    const float* x = (const float*)d_in[0];   // (64,512,1024) fp32
    const float* W = (const float*)d_in[1];   // (1024,1024) fp32
    float* out = (float*)d_out;               // (64,2048) fp32

    float* ws     = (float*)d_ws;             // needs ~8.7 MB
    float* v      = ws;                       // 65536
    float* partC  = ws + 65536;               // 2097152
    float* partML = ws + 65536 + (size_t)BB * NCHUNK * DD;  // 4096

    k_v<<<DD / 4, 256, 0, stream>>>(x, W, v);
    k_chunk<<<BB * NCHUNK, 256, 0, stream>>>(x, v, partC, partML);
    k_final<<<BB, 256, 0, stream>>>(x, partC, partML, out);
}

// Round 2
// 53.190 us; speedup vs baseline: 1.1058x; 1.1058x over previous
//
#include <hip/hip_runtime.h>
#include <math.h>

// Problem: B=64, T=512, D=1024.
//   v[b,d]     = sum_e W[d,e] * x[b,T-1,e]
//   scores[b,t]= sum_d x[b,t,d] * v[b,d]          (t in 0..510)
//   alpha      = softmax_t(scores)
//   c[b,d]     = sum_t alpha[b,t] * x[b,t,d]
//   out[b]     = concat(c[b,:], x[b,T-1,:])       (64 x 2048 fp32)

#define BB 64
#define TT 512
#define DD 1024
#define TH 511           // history rows
#define CHUNK 16         // t-rows per block in fused pass
#define NCHUNK 32        // ceil(511/16)

// workspace layout (floats):
//   v      : [BB][DD]              off 0        (65536)
//   partC  : [BB][NCHUNK][DD]      off 65536    (2097152)
//   partML : [BB][NCHUNK][2]       off 2162688  (4096)

// ---------------- kernel 1: v = x_last @ W^T -------------------------------
// 256 blocks x 4 waves; wave = 4 d-rows (W stationary, 64 VGPR) x 16 batches.
// x_last re-read total: 1024 waves * 64KB = 64MB from L2 (vs 256MB before).
__global__ __launch_bounds__(256, 4) void k_v(const float* __restrict__ x,
                                              const float* __restrict__ W,
                                              float* __restrict__ v) {
    const int wave = threadIdx.x >> 6;
    const int lane = threadIdx.x & 63;
    const int wg   = blockIdx.x * 4 + wave;   // 0..1023
    const int d0   = (wg >> 2) * 4;           // 256 d-quads
    const int bg   = wg & 3;                  // 4 batch-groups of 16

    float4 w4[4][4];
#pragma unroll
    for (int k = 0; k < 4; ++k)
#pragma unroll
        for (int j = 0; j < 4; ++j)
            w4[k][j] = *(const float4*)(W + (size_t)(d0 + k) * DD + j * 256 + lane * 4);

    float res = 0.f;                          // lane l -> (b = bg*16+(l>>2), d = d0+(l&3))
#pragma unroll 4
    for (int i = 0; i < 16; ++i) {
        const int b = bg * 16 + i;
        const float* xl = x + ((size_t)b * TT + (TT - 1)) * DD;
        float4 x4[4];
#pragma unroll
        for (int j = 0; j < 4; ++j)
            x4[j] = *(const float4*)(xl + j * 256 + lane * 4);
#pragma unroll
        for (int k = 0; k < 4; ++k) {
            float p = 0.f;
#pragma unroll
            for (int j = 0; j < 4; ++j)
                p += w4[k][j].x * x4[j].x + w4[k][j].y * x4[j].y +
                     w4[k][j].z * x4[j].z + w4[k][j].w * x4[j].w;
#pragma unroll
            for (int m = 1; m < 64; m <<= 1) p += __shfl_xor(p, m, 64);
            if (lane == i * 4 + k) res = p;
        }
    }
    v[(size_t)(bg * 16 + (lane >> 2)) * DD + d0 + (lane & 3)] = res;
}

// ---------------- kernel 2: fused scores -> chunk softmax -> partial c -----
// grid = BB*NCHUNK = 2048 blocks, 256 thr. x chunk register-resident:
// wave owns 4 full rows (16 float4/thread). LDS only 16KB combine buffer.
__global__ __launch_bounds__(256, 4) void k_chunk(const float* __restrict__ x,
                                                  const float* __restrict__ v,
                                                  float* __restrict__ partC,
                                                  float* __restrict__ partML) {
    __shared__ float cw[4][DD];               // 16 KB cross-wave combine
    __shared__ float sloc[CHUNK];
    __shared__ float eloc[CHUNK];
    __shared__ float mshare;

    const int b     = blockIdx.x >> 5;        // / NCHUNK
    const int c     = blockIdx.x & (NCHUNK - 1);
    const int wave  = threadIdx.x >> 6;
    const int lane  = threadIdx.x & 63;
    const int R     = min(CHUNK, TH - c * CHUNK);   // 16, last chunk 15
    const int rbase = wave * 4;

    float4 v4[4];
#pragma unroll
    for (int j = 0; j < 4; ++j)
        v4[j] = *(const float4*)(v + (size_t)b * DD + j * 256 + lane * 4);

    const float* xb = x + ((size_t)b * TT + (size_t)c * CHUNK) * DD;

    // phase A: load 4 rows into regs, dot with v
    float4 xr[4][4];
    float p[4];
#pragma unroll
    for (int rl = 0; rl < 4; ++rl) {
        const int r = rbase + rl;
        float pp = 0.f;
        if (r < R) {
#pragma unroll
            for (int j = 0; j < 4; ++j) {
                const float4 xv = *(const float4*)(xb + (size_t)r * DD + j * 256 + lane * 4);
                xr[rl][j] = xv;
                pp += v4[j].x * xv.x + v4[j].y * xv.y + v4[j].z * xv.z + v4[j].w * xv.w;
            }
        } else {
#pragma unroll
            for (int j = 0; j < 4; ++j) xr[rl][j] = make_float4(0.f, 0.f, 0.f, 0.f);
        }
        p[rl] = pp;
    }
#pragma unroll
    for (int rl = 0; rl < 4; ++rl)
#pragma unroll
        for (int m = 1; m < 64; m <<= 1) p[rl] += __shfl_xor(p[rl], m, 64);
    if (lane == 0) {
#pragma unroll
        for (int rl = 0; rl < 4; ++rl)
            if (rbase + rl < R) sloc[rbase + rl] = p[rl];
    }
    __syncthreads();

    // phase B: chunk softmax stats (threads 0..15)
    if (threadIdx.x < CHUNK) {
        float m = -INFINITY;
        for (int r = 0; r < R; ++r) m = fmaxf(m, sloc[r]);
        eloc[threadIdx.x] = (threadIdx.x < R) ? __expf(sloc[threadIdx.x] - m) : 0.f;
        if (threadIdx.x == 0) mshare = m;
    }
    __syncthreads();

    // phase C: weighted accumulate from registers
    float e[4];
#pragma unroll
    for (int rl = 0; rl < 4; ++rl) e[rl] = eloc[rbase + rl];
    float4 a4[4] = {make_float4(0,0,0,0), make_float4(0,0,0,0),
                    make_float4(0,0,0,0), make_float4(0,0,0,0)};
#pragma unroll
    for (int rl = 0; rl < 4; ++rl)
#pragma unroll
        for (int j = 0; j < 4; ++j) {
            a4[j].x += e[rl] * xr[rl][j].x;
            a4[j].y += e[rl] * xr[rl][j].y;
            a4[j].z += e[rl] * xr[rl][j].z;
            a4[j].w += e[rl] * xr[rl][j].w;
        }
#pragma unroll
    for (int j = 0; j < 4; ++j)
        *(float4*)(&cw[wave][j * 256 + lane * 4]) = a4[j];

    if (threadIdx.x == 0) {
        float l = 0.f;
        for (int r = 0; r < CHUNK; ++r) l += eloc[r];
        partML[((size_t)b * NCHUNK + c) * 2 + 0] = mshare;
        partML[((size_t)b * NCHUNK + c) * 2 + 1] = l;
    }
    __syncthreads();

    // cross-wave combine, write partial c
    const int d0 = threadIdx.x * 4;
    float4 s0 = *(const float4*)(&cw[0][d0]);
    const float4 s1 = *(const float4*)(&cw[1][d0]);
    const float4 s2 = *(const float4*)(&cw[2][d0]);
    const float4 s3 = *(const float4*)(&cw[3][d0]);
    s0.x += s1.x + s2.x + s3.x;
    s0.y += s1.y + s2.y + s3.y;
    s0.z += s1.z + s2.z + s3.z;
    s0.w += s1.w + s2.w + s3.w;
    *(float4*)(partC + ((size_t)b * NCHUNK + c) * DD + d0) = s0;
}

// ---------------- kernel 3: combine partials, divide, append x_last --------
// 256 blocks: (b, quarter-of-d). One float per thread.
__global__ __launch_bounds__(256) void k_final(const float* __restrict__ x,
                                               const float* __restrict__ partC,
                                               const float* __restrict__ partML,
                                               float* __restrict__ out) {
    const int b = blockIdx.x >> 2;
    const int q = blockIdx.x & 3;
    __shared__ float wgt[NCHUNK];
    __shared__ float lsh;

    if (threadIdx.x < NCHUNK) {
        float M = -INFINITY;
        for (int cc = 0; cc < NCHUNK; ++cc)
            M = fmaxf(M, partML[((size_t)b * NCHUNK + cc) * 2]);
        wgt[threadIdx.x] = __expf(partML[((size_t)b * NCHUNK + threadIdx.x) * 2] - M);
    }
    __syncthreads();
    if (threadIdx.x == 0) {
        float L = 0.f;
        for (int cc = 0; cc < NCHUNK; ++cc)
            L += partML[((size_t)b * NCHUNK + cc) * 2 + 1] * wgt[cc];
        lsh = 1.f / L;
    }
    __syncthreads();
    const float invL = lsh;

    const int d = q * 256 + threadIdx.x;
    float acc = 0.f;
#pragma unroll 8
    for (int cc = 0; cc < NCHUNK; ++cc)
        acc += wgt[cc] * partC[((size_t)b * NCHUNK + cc) * DD + d];
    out[(size_t)b * 2048 + d] = acc * invL;
    out[(size_t)b * 2048 + 1024 + d] = x[((size_t)b * TT + (TT - 1)) * DD + d];
}

extern "C" void kernel_launch(void* const* d_in, const int* in_sizes, int n_in,
                              void* d_out, int out_size, void* d_ws, size_t ws_size,
                              hipStream_t stream) {
    const float* x = (const float*)d_in[0];   // (64,512,1024) fp32
    const float* W = (const float*)d_in[1];   // (1024,1024) fp32
    float* out = (float*)d_out;               // (64,2048) fp32

    float* ws     = (float*)d_ws;             // ~8.7 MB
    float* v      = ws;                                           // 65536
    float* partC  = ws + 65536;                                   // 2097152
    float* partML = ws + 65536 + (size_t)BB * NCHUNK * DD;        // 4096

    k_v<<<256, 256, 0, stream>>>(x, W, v);
    k_chunk<<<BB * NCHUNK, 256, 0, stream>>>(x, v, partC, partML);
    k_final<<<BB * 4, 256, 0, stream>>>(x, partC, partML, out);
}